// Round 2
// baseline (520.007 us; speedup 1.0000x reference)
//
#include <hip/hip_runtime.h>
#include <stdint.h>

typedef __bf16 bf16x8 __attribute__((ext_vector_type(8)));
typedef float f32x4 __attribute__((ext_vector_type(4)));
typedef unsigned short ushort_t;

#define NPARENT 60000
#define NOUT (NPARENT*8)          // 480000 output rows
#define ZIDX NOUT                 // zero row index (missing neighbors)
#define TBL_N (66*66*66)          // parent table, coords shifted +1
#define NBIN 4096                 // 16^3 Morton bins of 4^3 cells

static constexpr size_t OFF_TABLE = 0;                                      // 1,152,000 (padded)
static constexpr size_t OFF_CS    = 1152000;                                // int4 sorted coords, 960,000 B
static constexpr size_t OFF_Y     = OFF_CS + 960000;
// hist/cnt alias the head of Y: used only before k_up overwrites Y
static constexpr size_t OFF_HIST  = OFF_Y;
static constexpr size_t OFF_CNT   = OFF_Y + 16384;
static constexpr size_t OFF_Z     = OFF_Y + (size_t)(NOUT+1)*128;
static constexpr size_t OFF_FEATB = OFF_Z + (size_t)(NOUT+1)*128;
static constexpr size_t OFF_WUPF  = OFF_FEATB + (size_t)NPARENT*128;
static constexpr size_t OFF_W1F   = OFF_WUPF + (size_t)8*8192;
static constexpr size_t OFF_W2F   = OFF_W1F + (size_t)27*8192;
static constexpr size_t WS_NEED   = OFF_W2F + (size_t)27*8192;              // ~133.2 MB

__device__ __forceinline__ ushort_t f2bf(float x) {   // RNE float->bf16
  uint32_t u = __float_as_uint(x);
  u += 0x7fffu + ((u >> 16) & 1u);
  return (ushort_t)(u >> 16);
}

__device__ __forceinline__ int binof(int x, int y, int z) {  // 12-bit Morton of 4-cell bins
  int bx = x >> 2, by = y >> 2, bz = z >> 2, m = 0;
  #pragma unroll
  for (int b = 0; b < 4; ++b)
    m |= (((bx>>b)&1) << (3*b+2)) | (((by>>b)&1) << (3*b+1)) | (((bz>>b)&1) << (3*b));
  return m;
}

__global__ void k_zero(ushort_t* y, ushort_t* z) {
  int t = threadIdx.x;
  if (t < 64) y[(size_t)ZIDX*64 + t] = 0;
  else        z[(size_t)ZIDX*64 + (t-64)] = 0;
}

__global__ void k_hist(const int* __restrict__ coords, int* __restrict__ hist) {
  int i = blockIdx.x*blockDim.x + threadIdx.x;
  if (i >= NPARENT) return;
  atomicAdd(&hist[binof(coords[3*i], coords[3*i+1], coords[3*i+2])], 1);
}

__global__ void k_scan(const int* __restrict__ hist, int* __restrict__ cnt) {
  __shared__ int s[256];
  int t = threadIdx.x;
  int loc[16], sum = 0;
  #pragma unroll
  for (int j=0;j<16;++j){ loc[j]=hist[t*16+j]; sum+=loc[j]; }
  s[t]=sum;
  __syncthreads();
  if (t==0){ int a=0; for (int i=0;i<256;++i){ int v=s[i]; s[i]=a; a+=v; } }
  __syncthreads();
  int a=s[t];
  #pragma unroll
  for (int j=0;j<16;++j){ cnt[t*16+j]=a; a+=loc[j]; }
}

// rank parents into Morton-bin order; emit packed sorted coords + orig idx, fill table with rank
__global__ void k_rank(const int* __restrict__ coords, int* __restrict__ cnt,
                       int4* __restrict__ cs, int* __restrict__ tbl) {
  int i = blockIdx.x*blockDim.x + threadIdx.x;
  if (i >= NPARENT) return;
  int x = coords[3*i], y = coords[3*i+1], z = coords[3*i+2];
  int r = atomicAdd(&cnt[binof(x,y,z)], 1);
  cs[r] = make_int4(x, y, z, i);
  tbl[((x+1)*66 + (y+1))*66 + (z+1)] = r;
}

// feats f32 -> bf16, gathered into sorted parent order
__global__ void k_feats_bf16(const float4* __restrict__ f, const int4* __restrict__ cs,
                             ushort_t* __restrict__ o, int total) {
  int t = blockIdx.x*blockDim.x + threadIdx.x;
  if (t >= total) return;
  int p = t >> 4, q = t & 15;
  int i = cs[p].w;
  float4 v = f[(size_t)i*16 + q];
  size_t ob = (size_t)p*64 + q*4;
  o[ob+0] = f2bf(v.x); o[ob+1] = f2bf(v.y);
  o[ob+2] = f2bf(v.z); o[ob+3] = f2bf(v.w);
}

// W[k][c][d] f32 -> bf16 in MFMA B-fragment order:
// frag f = ks*4+nt, lane = ((c>>3)&3)*16 + (d&15), elem e = c&7
__global__ void k_wfrag(const float* __restrict__ w, ushort_t* __restrict__ o, int total) {
  int i = blockIdx.x*blockDim.x + threadIdx.x;
  if (i >= total) return;
  int k = i >> 12, r = i & 4095, c = r >> 6, d = r & 63;
  int nt = d >> 4, lp = d & 15, ks = c >> 5, hi = (c >> 3) & 3, e = c & 7;
  int fi = ks*4 + nt, lane = hi*16 + lp;
  o[(size_t)(k*8 + fi)*512 + lane*8 + e] = f2bf(w[i]);
}

// up-projection: y[8p+c8] = relu(feats_sorted[p] @ W_up[c8] + b_up), stored bf16
__global__ __launch_bounds__(256) void k_up(const ushort_t* __restrict__ featb,
    const ushort_t* __restrict__ wupf, const float* __restrict__ bup,
    ushort_t* __restrict__ y)
{
  int wave = threadIdx.x >> 6, lane = threadIdx.x & 63;
  int n0 = blockIdx.x*64 + wave*16;
  if (n0 >= NPARENT) return;
  int lp = lane & 15, hi = lane >> 4;
  const ushort_t* ar = featb + (size_t)(n0+lp)*64 + hi*8;
  bf16x8 a0 = *(const bf16x8*)(ar);
  bf16x8 a1 = *(const bf16x8*)(ar + 32);
  float bv[4];
  #pragma unroll
  for (int nt=0; nt<4; ++nt) bv[nt] = bup[nt*16+lp];
  for (int c8=0; c8<8; ++c8) {
    const ushort_t* wb = wupf + (size_t)c8*4096 + lane*8;
    f32x4 acc[4];
    #pragma unroll
    for (int nt=0;nt<4;++nt) acc[nt] = (f32x4){0.f,0.f,0.f,0.f};
    #pragma unroll
    for (int nt=0;nt<4;++nt)
      acc[nt] = __builtin_amdgcn_mfma_f32_16x16x32_bf16(a0, *(const bf16x8*)(wb + nt*512), acc[nt], 0,0,0);
    #pragma unroll
    for (int nt=0;nt<4;++nt)
      acc[nt] = __builtin_amdgcn_mfma_f32_16x16x32_bf16(a1, *(const bf16x8*)(wb + (4+nt)*512), acc[nt], 0,0,0);
    #pragma unroll
    for (int nt=0;nt<4;++nt) {
      #pragma unroll
      for (int j=0;j<4;++j) {
        int par = n0 + hi*4 + j;
        float v = acc[nt][j] + bv[nt];
        v = fmaxf(v, 0.f);
        y[(size_t)(par*8 + c8)*64 + nt*16 + lp] = f2bf(v);
      }
    }
  }
}

// sparse stride-1 conv as gather-GEMM over sorted rows. Wave = 64 rows x 64 cols.
template<int RELU, int SCATTER, typename OUT_T>
__global__ __launch_bounds__(256) void k_conv(const int4* __restrict__ cs,
    const int* __restrict__ tbl, const ushort_t* __restrict__ fin,
    const ushort_t* __restrict__ wf, const float* __restrict__ bias,
    OUT_T* __restrict__ out)
{
  // bijective XCD swizzle: nwg = 1875 = 8*234+3 (m204 variant)
  int bid = blockIdx.x;
  int xcd = bid & 7, jj = bid >> 3;
  int wg = (xcd < 3 ? xcd*235 : 705 + (xcd-3)*234) + jj;

  int wave = threadIdx.x >> 6, lane = threadIdx.x & 63;
  int m0 = wg*256 + wave*64;
  int lp = lane & 15, hi = lane >> 4;

  // per-subtile row geometry (sorted order): out v = 2*parent + child bits
  int vx2[4], vy2[4], vz2[4], par[4];
  #pragma unroll
  for (int s=0;s<4;++s) {
    int r = m0 + s*16 + lp;
    int4 cc = cs[r >> 3];
    int c = r & 7;
    par[s] = c;
    vx2[s] = 2*cc.x + ((c>>2)&1) + 2;
    vy2[s] = 2*cc.y + ((c>>1)&1) + 2;
    vz2[s] = 2*cc.z + (c&1) + 2;
  }

  f32x4 acc[4][4];
  #pragma unroll
  for (int s=0;s<4;++s)
    #pragma unroll
    for (int nt=0;nt<4;++nt) acc[s][nt] = (f32x4){0.f,0.f,0.f,0.f};

  const char* finl  = (const char*)fin + hi*16;
  const char* wbase = (const char*)wf + lane*16;

  auto nbr = [&](int ox, int oy, int oz, int s) -> uint32_t {
    int lin = (int)__umul24((unsigned)((vx2[s]+ox)>>1), 4356u)
            + (int)__umul24((unsigned)((vy2[s]+oy)>>1), 66u)
            + ((vz2[s]+oz)>>1);
    int pidx = tbl[lin];
    int xk = ((ox&1)<<2) | ((oy&1)<<1) | (oz&1);
    uint32_t off = (uint32_t)(pidx*8 + (par[s]^xk)) * 128u;
    return (pidx < 0) ? (uint32_t)ZIDX*128u : off;
  };

  uint32_t aoff[4];
  #pragma unroll
  for (int s=0;s<4;++s) aoff[s] = nbr(-1,-1,-1,s);

  #pragma unroll 1
  for (int k=0;k<27;++k) {
    const char* wk = wbase + k*8192;
    bf16x8 bfr[8];
    #pragma unroll
    for (int f=0;f<8;++f) bfr[f] = *(const bf16x8*)(wk + f*1024);
    bf16x8 a[4][2];
    #pragma unroll
    for (int s=0;s<4;++s) {
      a[s][0] = *(const bf16x8*)(finl + aoff[s]);
      a[s][1] = *(const bf16x8*)(finl + aoff[s] + 64);
    }
    if (k < 26) {   // next offset's table lookups hidden under the MFMAs
      int k2 = k+1;
      int ox = k2/9 - 1, oy = (k2/3)%3 - 1, oz = k2%3 - 1;
      #pragma unroll
      for (int s=0;s<4;++s) aoff[s] = nbr(ox,oy,oz,s);
    }
    #pragma unroll
    for (int s=0;s<4;++s)
      #pragma unroll
      for (int nt=0;nt<4;++nt)
        acc[s][nt] = __builtin_amdgcn_mfma_f32_16x16x32_bf16(a[s][0], bfr[nt], acc[s][nt], 0,0,0);
    #pragma unroll
    for (int s=0;s<4;++s)
      #pragma unroll
      for (int nt=0;nt<4;++nt)
        acc[s][nt] = __builtin_amdgcn_mfma_f32_16x16x32_bf16(a[s][1], bfr[4+nt], acc[s][nt], 0,0,0);
  }

  float bv[4];
  #pragma unroll
  for (int nt=0;nt<4;++nt) bv[nt] = bias[nt*16+lp];
  #pragma unroll
  for (int s=0;s<4;++s) {
    #pragma unroll
    for (int j=0;j<4;++j) {
      int row = m0 + s*16 + hi*4 + j;
      size_t rb;
      if constexpr (SCATTER) {
        int4 cc = cs[row >> 3];
        rb = ((size_t)cc.w*8 + (row & 7)) * 64;
      } else {
        rb = (size_t)row * 64;
      }
      #pragma unroll
      for (int nt=0;nt<4;++nt) {
        float v = acc[s][nt][j] + bv[nt];
        if (RELU) v = fmaxf(v, 0.f);
        size_t oi = rb + nt*16 + lp;
        if constexpr (sizeof(OUT_T)==2) ((ushort_t*)out)[oi] = f2bf(v);
        else                            out[oi] = v;
      }
    }
  }
}

extern "C" void kernel_launch(void* const* d_in, const int* in_sizes, int n_in,
                              void* d_out, int out_size, void* d_ws, size_t ws_size,
                              hipStream_t stream) {
  const int*   coords = (const int*)d_in[0];
  const float* feats  = (const float*)d_in[1];
  const float* Wup    = (const float*)d_in[2];
  const float* bup    = (const float*)d_in[3];
  const float* W1     = (const float*)d_in[4];
  const float* b1     = (const float*)d_in[5];
  const float* W2     = (const float*)d_in[6];
  const float* b2     = (const float*)d_in[7];
  char* ws = (char*)d_ws;
  if (ws_size < WS_NEED) return;   // fail visibly rather than corrupt

  int*      tbl  = (int*)(ws + OFF_TABLE);
  int4*     cs   = (int4*)(ws + OFF_CS);
  int*      hist = (int*)(ws + OFF_HIST);
  int*      cnt  = (int*)(ws + OFF_CNT);
  ushort_t* y    = (ushort_t*)(ws + OFF_Y);
  ushort_t* z    = (ushort_t*)(ws + OFF_Z);
  ushort_t* fb   = (ushort_t*)(ws + OFF_FEATB);
  ushort_t* wupf = (ushort_t*)(ws + OFF_WUPF);
  ushort_t* w1f  = (ushort_t*)(ws + OFF_W1F);
  ushort_t* w2f  = (ushort_t*)(ws + OFF_W2F);

  hipMemsetAsync(tbl, 0xFF, (size_t)TBL_N*4, stream);
  hipMemsetAsync(hist, 0, (size_t)NBIN*4, stream);
  k_zero<<<1,128,0,stream>>>(y, z);
  k_hist<<<(NPARENT+255)/256,256,0,stream>>>(coords, hist);
  k_scan<<<1,256,0,stream>>>(hist, cnt);
  k_rank<<<(NPARENT+255)/256,256,0,stream>>>(coords, cnt, cs, tbl);
  k_feats_bf16<<<(NPARENT*16+255)/256,256,0,stream>>>((const float4*)feats, cs, fb, NPARENT*16);
  k_wfrag<<<(8*4096+255)/256,256,0,stream>>>(Wup, wupf, 8*4096);
  k_wfrag<<<(27*4096+255)/256,256,0,stream>>>(W1, w1f, 27*4096);
  k_wfrag<<<(27*4096+255)/256,256,0,stream>>>(W2, w2f, 27*4096);
  k_up<<<(NPARENT+63)/64,256,0,stream>>>(fb, wupf, bup, y);
  k_conv<1,0,ushort_t><<<NOUT/256,256,0,stream>>>(cs, tbl, y,  w1f, b1, z);
  k_conv<0,1,float>   <<<NOUT/256,256,0,stream>>>(cs, tbl, z,  w2f, b2, (float*)d_out);
}

// Round 3
// 379.971 us; speedup vs baseline: 1.3685x; 1.3685x over previous
//
#include <hip/hip_runtime.h>
#include <stdint.h>

typedef __bf16 bf16x8 __attribute__((ext_vector_type(8)));
typedef float f32x4 __attribute__((ext_vector_type(4)));
typedef unsigned short ushort_t;

#define NPARENT 60000
#define NOUT (NPARENT*8)          // 480000 output rows
#define ZIDX NOUT                 // zero row index (missing neighbors)
#define TBL_N (66*66*66)          // parent table, coords shifted +1
#define NBIN 4096                 // 16^3 Morton bins of 4^3 cells

static constexpr size_t OFF_TABLE = 0;                                      // 1,152,000 (padded)
static constexpr size_t OFF_CS    = 1152000;                                // int4 sorted coords, 960,000 B
static constexpr size_t OFF_Y     = OFF_CS + 960000;
// hist/cnt alias the head of Y: used only before k_up overwrites Y
static constexpr size_t OFF_HIST  = OFF_Y;
static constexpr size_t OFF_CNT   = OFF_Y + 16384;
static constexpr size_t OFF_Z     = OFF_Y + (size_t)(NOUT+1)*128;
static constexpr size_t OFF_FEATB = OFF_Z + (size_t)(NOUT+1)*128;
static constexpr size_t OFF_WUPF  = OFF_FEATB + (size_t)NPARENT*128;
static constexpr size_t OFF_W1F   = OFF_WUPF + (size_t)8*8192;
static constexpr size_t OFF_W2F   = OFF_W1F + (size_t)27*8192;
static constexpr size_t WS_NEED   = OFF_W2F + (size_t)27*8192;              // ~133.2 MB

__device__ __forceinline__ ushort_t f2bf(float x) {   // RNE float->bf16
  uint32_t u = __float_as_uint(x);
  u += 0x7fffu + ((u >> 16) & 1u);
  return (ushort_t)(u >> 16);
}

__device__ __forceinline__ int binof(int x, int y, int z) {  // 12-bit Morton of 4-cell bins
  int bx = x >> 2, by = y >> 2, bz = z >> 2, m = 0;
  #pragma unroll
  for (int b = 0; b < 4; ++b)
    m |= (((bx>>b)&1) << (3*b+2)) | (((by>>b)&1) << (3*b+1)) | (((bz>>b)&1) << (3*b));
  return m;
}

// async global->LDS, 16B per lane. dst is wave-uniform base (HW adds lane*16),
// src is this lane's global address.
__device__ __forceinline__ void gl2lds16(const void* g, void* l) {
  __builtin_amdgcn_global_load_lds(
      (const __attribute__((address_space(1))) uint32_t*)g,
      (__attribute__((address_space(3))) uint32_t*)l, 16, 0, 0);
}

__global__ void k_zero(ushort_t* y, ushort_t* z) {
  int t = threadIdx.x;
  if (t < 64) y[(size_t)ZIDX*64 + t] = 0;
  else        z[(size_t)ZIDX*64 + (t-64)] = 0;
}

__global__ void k_hist(const int* __restrict__ coords, int* __restrict__ hist) {
  int i = blockIdx.x*blockDim.x + threadIdx.x;
  if (i >= NPARENT) return;
  atomicAdd(&hist[binof(coords[3*i], coords[3*i+1], coords[3*i+2])], 1);
}

__global__ void k_scan(const int* __restrict__ hist, int* __restrict__ cnt) {
  __shared__ int s[256];
  int t = threadIdx.x;
  int loc[16], sum = 0;
  #pragma unroll
  for (int j=0;j<16;++j){ loc[j]=hist[t*16+j]; sum+=loc[j]; }
  s[t]=sum;
  __syncthreads();
  if (t==0){ int a=0; for (int i=0;i<256;++i){ int v=s[i]; s[i]=a; a+=v; } }
  __syncthreads();
  int a=s[t];
  #pragma unroll
  for (int j=0;j<16;++j){ cnt[t*16+j]=a; a+=loc[j]; }
}

// rank parents into Morton-bin order; emit packed sorted coords + orig idx, fill table with rank
__global__ void k_rank(const int* __restrict__ coords, int* __restrict__ cnt,
                       int4* __restrict__ cs, int* __restrict__ tbl) {
  int i = blockIdx.x*blockDim.x + threadIdx.x;
  if (i >= NPARENT) return;
  int x = coords[3*i], y = coords[3*i+1], z = coords[3*i+2];
  int r = atomicAdd(&cnt[binof(x,y,z)], 1);
  cs[r] = make_int4(x, y, z, i);
  tbl[((x+1)*66 + (y+1))*66 + (z+1)] = r;
}

// feats f32 -> bf16, gathered into sorted parent order
__global__ void k_feats_bf16(const float4* __restrict__ f, const int4* __restrict__ cs,
                             ushort_t* __restrict__ o, int total) {
  int t = blockIdx.x*blockDim.x + threadIdx.x;
  if (t >= total) return;
  int p = t >> 4, q = t & 15;
  int i = cs[p].w;
  float4 v = f[(size_t)i*16 + q];
  size_t ob = (size_t)p*64 + q*4;
  o[ob+0] = f2bf(v.x); o[ob+1] = f2bf(v.y);
  o[ob+2] = f2bf(v.z); o[ob+3] = f2bf(v.w);
}

// W[k][c][d] f32 -> bf16 in MFMA B-fragment order:
// frag f = ks*4+nt, lane = ((c>>3)&3)*16 + (d&15), elem e = c&7
__global__ void k_wfrag(const float* __restrict__ w, ushort_t* __restrict__ o, int total) {
  int i = blockIdx.x*blockDim.x + threadIdx.x;
  if (i >= total) return;
  int k = i >> 12, r = i & 4095, c = r >> 6, d = r & 63;
  int nt = d >> 4, lp = d & 15, ks = c >> 5, hi = (c >> 3) & 3, e = c & 7;
  int fi = ks*4 + nt, lane = hi*16 + lp;
  o[(size_t)(k*8 + fi)*512 + lane*8 + e] = f2bf(w[i]);
}

// up-projection: y[8p+c8] = relu(feats_sorted[p] @ W_up[c8] + b_up), stored bf16
__global__ __launch_bounds__(256) void k_up(const ushort_t* __restrict__ featb,
    const ushort_t* __restrict__ wupf, const float* __restrict__ bup,
    ushort_t* __restrict__ y)
{
  int wave = threadIdx.x >> 6, lane = threadIdx.x & 63;
  int n0 = blockIdx.x*64 + wave*16;
  if (n0 >= NPARENT) return;
  int lp = lane & 15, hi = lane >> 4;
  const ushort_t* ar = featb + (size_t)(n0+lp)*64 + hi*8;
  bf16x8 a0 = *(const bf16x8*)(ar);
  bf16x8 a1 = *(const bf16x8*)(ar + 32);
  float bv[4];
  #pragma unroll
  for (int nt=0; nt<4; ++nt) bv[nt] = bup[nt*16+lp];
  for (int c8=0; c8<8; ++c8) {
    const ushort_t* wb = wupf + (size_t)c8*4096 + lane*8;
    f32x4 acc[4];
    #pragma unroll
    for (int nt=0;nt<4;++nt) acc[nt] = (f32x4){0.f,0.f,0.f,0.f};
    #pragma unroll
    for (int nt=0;nt<4;++nt)
      acc[nt] = __builtin_amdgcn_mfma_f32_16x16x32_bf16(a0, *(const bf16x8*)(wb + nt*512), acc[nt], 0,0,0);
    #pragma unroll
    for (int nt=0;nt<4;++nt)
      acc[nt] = __builtin_amdgcn_mfma_f32_16x16x32_bf16(a1, *(const bf16x8*)(wb + (4+nt)*512), acc[nt], 0,0,0);
    #pragma unroll
    for (int nt=0;nt<4;++nt) {
      #pragma unroll
      for (int j=0;j<4;++j) {
        int par = n0 + hi*4 + j;
        float v = acc[nt][j] + bv[nt];
        v = fmaxf(v, 0.f);
        y[(size_t)(par*8 + c8)*64 + nt*16 + lp] = f2bf(v);
      }
    }
  }
}

// sparse stride-1 conv as gather-GEMM over sorted rows. Wave = 64 rows x 64 cols.
// TA-pressure reduction: neighbor ranks cached in LDS per block (zero TA in loop),
// B fragments LDS-double-buffered via global_load_lds (4x dedup across waves).
template<int RELU, int SCATTER, typename OUT_T>
__global__ __launch_bounds__(256) void k_conv(const int4* __restrict__ cs,
    const int* __restrict__ tbl, const ushort_t* __restrict__ fin,
    const ushort_t* __restrict__ wf, const float* __restrict__ bias,
    OUT_T* __restrict__ out)
{
  __shared__ __align__(16) int nbrs[32*27];          // block parents x 27 neighbor ranks
  __shared__ __align__(16) ushort_t bbuf[2][4096];   // 8KB B double buffer

  // bijective XCD swizzle: nwg = 1875 = 8*234+3 (m204 variant)
  int bid = blockIdx.x;
  int xcd = bid & 7, jj = bid >> 3;
  int wg = (xcd < 3 ? xcd*235 : 705 + (xcd-3)*234) + jj;

  int tid = threadIdx.x;
  int wave = tid >> 6, lane = tid & 63;
  int m0 = wg*256 + wave*64;
  int lp = lane & 15, hi = lane >> 4;
  int pblk0 = wg*32;                                  // block's first sorted parent

  // ---- one-time: build neighbor-rank cache (864 entries) ----
  for (int i = tid; i < 32*27; i += 256) {
    int p = i / 27, j = i - p*27;
    int4 cc = cs[pblk0 + p];
    int dx = j/9 - 1, dy = (j/3)%3 - 1, dz = j%3 - 1;
    nbrs[i] = tbl[((cc.x+dx+1)*66 + (cc.y+dy+1))*66 + (cc.z+dz+1)];
  }

  // ---- stage B for k=0 into buf 0 (each wave stages 2 of 8 1KB chunks) ----
  {
    const char* wb = (const char*)wf;
    #pragma unroll
    for (int j=0;j<2;++j) {
      int chunk = wave*2 + j;
      gl2lds16(wb + (size_t)chunk*1024 + lane*16, &bbuf[0][chunk*512]);
    }
  }

  // per-lane constants: child bits (constant across subtiles), parent base
  int cx = (lp>>2)&1, cy = (lp>>1)&1, cz = lp&1, c = lp&7;
  int plbase = wave*8 + (lp>>3);                      // block-local parent, + s*2 per subtile

  f32x4 acc[4][4];
  #pragma unroll
  for (int s=0;s<4;++s)
    #pragma unroll
    for (int nt=0;nt<4;++nt) acc[s][nt] = (f32x4){0.f,0.f,0.f,0.f};

  const char* finl = (const char*)fin + hi*16;

  __syncthreads();   // nbrs + buf0 ready (barrier drains vmcnt)

  #pragma unroll 1
  for (int k=0;k<27;++k) {
    int cur = k & 1;
    // uniform offset decode for this k
    int ox = k/9 - 1, oy = (k/3)%3 - 1, oz = k%3 - 1;
    int xk = ((ox&1)<<2) | ((oy&1)<<1) | (oz&1);
    int cpx = c ^ xk;
    // per-subtile A offsets from LDS neighbor cache (no TA traffic)
    uint32_t aoff[4];
    #pragma unroll
    for (int s=0;s<4;++s) {
      int idx = ((cx+ox)>>1)*9 + ((cy+oy)>>1)*3 + ((cz+oz)>>1) + 13;  // (j+1) folded
      int rank = nbrs[(plbase + s*2)*27 + idx];
      uint32_t off = (uint32_t)(rank*8 + cpx) * 128u;
      aoff[s] = (rank < 0) ? (uint32_t)ZIDX*128u : off;
    }
    // issue A gathers first (MFMA wait leaves later stage-loads in flight)
    bf16x8 a[4][2];
    #pragma unroll
    for (int s=0;s<4;++s) {
      a[s][0] = *(const bf16x8*)(finl + aoff[s]);
      a[s][1] = *(const bf16x8*)(finl + aoff[s] + 64);
    }
    // stage next k's B chunks into the other buffer
    if (k < 26) {
      const char* wb = (const char*)wf + (size_t)(k+1)*8192;
      #pragma unroll
      for (int j=0;j<2;++j) {
        int chunk = wave*2 + j;
        gl2lds16(wb + (size_t)chunk*1024 + lane*16, &bbuf[cur^1][chunk*512]);
      }
    }
    // B fragments from LDS (stride-16B, conflict-free)
    bf16x8 bfr[8];
    #pragma unroll
    for (int f=0;f<8;++f) bfr[f] = *(const bf16x8*)&bbuf[cur][f*512 + lane*8];

    #pragma unroll
    for (int s=0;s<4;++s)
      #pragma unroll
      for (int nt=0;nt<4;++nt)
        acc[s][nt] = __builtin_amdgcn_mfma_f32_16x16x32_bf16(a[s][0], bfr[nt], acc[s][nt], 0,0,0);
    #pragma unroll
    for (int s=0;s<4;++s)
      #pragma unroll
      for (int nt=0;nt<4;++nt)
        acc[s][nt] = __builtin_amdgcn_mfma_f32_16x16x32_bf16(a[s][1], bfr[4+nt], acc[s][nt], 0,0,0);

    __syncthreads();   // drains stage loads; buf[cur^1] ready for next k
  }

  float bv[4];
  #pragma unroll
  for (int nt=0;nt<4;++nt) bv[nt] = bias[nt*16+lp];
  #pragma unroll
  for (int s=0;s<4;++s) {
    #pragma unroll
    for (int j=0;j<4;++j) {
      int row = m0 + s*16 + hi*4 + j;
      size_t rb;
      if constexpr (SCATTER) {
        int4 cc = cs[row >> 3];
        rb = ((size_t)cc.w*8 + (row & 7)) * 64;
      } else {
        rb = (size_t)row * 64;
      }
      #pragma unroll
      for (int nt=0;nt<4;++nt) {
        float v = acc[s][nt][j] + bv[nt];
        if (RELU) v = fmaxf(v, 0.f);
        size_t oi = rb + nt*16 + lp;
        if constexpr (sizeof(OUT_T)==2) ((ushort_t*)out)[oi] = f2bf(v);
        else                            out[oi] = v;
      }
    }
  }
}

extern "C" void kernel_launch(void* const* d_in, const int* in_sizes, int n_in,
                              void* d_out, int out_size, void* d_ws, size_t ws_size,
                              hipStream_t stream) {
  const int*   coords = (const int*)d_in[0];
  const float* feats  = (const float*)d_in[1];
  const float* Wup    = (const float*)d_in[2];
  const float* bup    = (const float*)d_in[3];
  const float* W1     = (const float*)d_in[4];
  const float* b1     = (const float*)d_in[5];
  const float* W2     = (const float*)d_in[6];
  const float* b2     = (const float*)d_in[7];
  char* ws = (char*)d_ws;
  if (ws_size < WS_NEED) return;   // fail visibly rather than corrupt

  int*      tbl  = (int*)(ws + OFF_TABLE);
  int4*     cs   = (int4*)(ws + OFF_CS);
  int*      hist = (int*)(ws + OFF_HIST);
  int*      cnt  = (int*)(ws + OFF_CNT);
  ushort_t* y    = (ushort_t*)(ws + OFF_Y);
  ushort_t* z    = (ushort_t*)(ws + OFF_Z);
  ushort_t* fb   = (ushort_t*)(ws + OFF_FEATB);
  ushort_t* wupf = (ushort_t*)(ws + OFF_WUPF);
  ushort_t* w1f  = (ushort_t*)(ws + OFF_W1F);
  ushort_t* w2f  = (ushort_t*)(ws + OFF_W2F);

  hipMemsetAsync(tbl, 0xFF, (size_t)TBL_N*4, stream);
  hipMemsetAsync(hist, 0, (size_t)NBIN*4, stream);
  k_zero<<<1,128,0,stream>>>(y, z);
  k_hist<<<(NPARENT+255)/256,256,0,stream>>>(coords, hist);
  k_scan<<<1,256,0,stream>>>(hist, cnt);
  k_rank<<<(NPARENT+255)/256,256,0,stream>>>(coords, cnt, cs, tbl);
  k_feats_bf16<<<(NPARENT*16+255)/256,256,0,stream>>>((const float4*)feats, cs, fb, NPARENT*16);
  k_wfrag<<<(8*4096+255)/256,256,0,stream>>>(Wup, wupf, 8*4096);
  k_wfrag<<<(27*4096+255)/256,256,0,stream>>>(W1, w1f, 27*4096);
  k_wfrag<<<(27*4096+255)/256,256,0,stream>>>(W2, w2f, 27*4096);
  k_up<<<(NPARENT+63)/64,256,0,stream>>>(fb, wupf, bup, y);
  k_conv<1,0,ushort_t><<<NOUT/256,256,0,stream>>>(cs, tbl, y,  w1f, b1, z);
  k_conv<0,1,float>   <<<NOUT/256,256,0,stream>>>(cs, tbl, z,  w2f, b2, (float*)d_out);
}

// Round 4
// 377.535 us; speedup vs baseline: 1.3774x; 1.0065x over previous
//
#include <hip/hip_runtime.h>
#include <stdint.h>

typedef __bf16 bf16x8 __attribute__((ext_vector_type(8)));
typedef float f32x4 __attribute__((ext_vector_type(4)));
typedef unsigned short ushort_t;

#define NPARENT 60000
#define NOUT (NPARENT*8)          // 480000 output rows
#define ZIDX NOUT                 // zero row index (missing neighbors)
#define TBL_N (66*66*66)          // parent table, coords shifted +1
#define NBIN 4096                 // 16^3 Morton bins of 4^3 cells

static constexpr size_t OFF_TABLE = 0;                                      // 1,152,000 (padded)
static constexpr size_t OFF_CS    = 1152000;                                // int4 sorted coords, 960,000 B
static constexpr size_t OFF_Y     = OFF_CS + 960000;
// hist/cnt alias the head of Y: used only before k_up overwrites Y
static constexpr size_t OFF_HIST  = OFF_Y;
static constexpr size_t OFF_CNT   = OFF_Y + 16384;
static constexpr size_t OFF_Z     = OFF_Y + (size_t)(NOUT+1)*128;
static constexpr size_t OFF_FEATB = OFF_Z + (size_t)(NOUT+1)*128;
static constexpr size_t OFF_WUPF  = OFF_FEATB + (size_t)NPARENT*128;
static constexpr size_t OFF_W1F   = OFF_WUPF + (size_t)8*8192;
static constexpr size_t OFF_W2F   = OFF_W1F + (size_t)27*8192;
static constexpr size_t WS_NEED   = OFF_W2F + (size_t)27*8192;              // ~133.2 MB

__device__ __forceinline__ ushort_t f2bf(float x) {   // RNE float->bf16
  uint32_t u = __float_as_uint(x);
  u += 0x7fffu + ((u >> 16) & 1u);
  return (ushort_t)(u >> 16);
}

__device__ __forceinline__ int binof(int x, int y, int z) {  // 12-bit Morton of 4-cell bins
  int bx = x >> 2, by = y >> 2, bz = z >> 2, m = 0;
  #pragma unroll
  for (int b = 0; b < 4; ++b)
    m |= (((bx>>b)&1) << (3*b+2)) | (((by>>b)&1) << (3*b+1)) | (((bz>>b)&1) << (3*b));
  return m;
}

// async global->LDS, 16B per lane. dst is wave-uniform base (HW adds lane*16),
// src is this lane's global address.
__device__ __forceinline__ void gl2lds16(const void* g, void* l) {
  __builtin_amdgcn_global_load_lds(
      (const __attribute__((address_space(1))) uint32_t*)g,
      (__attribute__((address_space(3))) uint32_t*)l, 16, 0, 0);
}

__global__ void k_zero(ushort_t* y, ushort_t* z) {
  int t = threadIdx.x;
  if (t < 64) y[(size_t)ZIDX*64 + t] = 0;
  else        z[(size_t)ZIDX*64 + (t-64)] = 0;
}

__global__ void k_hist(const int* __restrict__ coords, int* __restrict__ hist) {
  int i = blockIdx.x*blockDim.x + threadIdx.x;
  if (i >= NPARENT) return;
  atomicAdd(&hist[binof(coords[3*i], coords[3*i+1], coords[3*i+2])], 1);
}

__global__ void k_scan(const int* __restrict__ hist, int* __restrict__ cnt) {
  __shared__ int s[256];
  int t = threadIdx.x;
  int loc[16], sum = 0;
  #pragma unroll
  for (int j=0;j<16;++j){ loc[j]=hist[t*16+j]; sum+=loc[j]; }
  s[t]=sum;
  __syncthreads();
  if (t==0){ int a=0; for (int i=0;i<256;++i){ int v=s[i]; s[i]=a; a+=v; } }
  __syncthreads();
  int a=s[t];
  #pragma unroll
  for (int j=0;j<16;++j){ cnt[t*16+j]=a; a+=loc[j]; }
}

// rank parents into Morton-bin order; emit packed sorted coords + orig idx, fill table with rank
__global__ void k_rank(const int* __restrict__ coords, int* __restrict__ cnt,
                       int4* __restrict__ cs, int* __restrict__ tbl) {
  int i = blockIdx.x*blockDim.x + threadIdx.x;
  if (i >= NPARENT) return;
  int x = coords[3*i], y = coords[3*i+1], z = coords[3*i+2];
  int r = atomicAdd(&cnt[binof(x,y,z)], 1);
  cs[r] = make_int4(x, y, z, i);
  tbl[((x+1)*66 + (y+1))*66 + (z+1)] = r;
}

// feats f32 -> bf16, gathered into sorted parent order
__global__ void k_feats_bf16(const float4* __restrict__ f, const int4* __restrict__ cs,
                             ushort_t* __restrict__ o, int total) {
  int t = blockIdx.x*blockDim.x + threadIdx.x;
  if (t >= total) return;
  int p = t >> 4, q = t & 15;
  int i = cs[p].w;
  float4 v = f[(size_t)i*16 + q];
  size_t ob = (size_t)p*64 + q*4;
  o[ob+0] = f2bf(v.x); o[ob+1] = f2bf(v.y);
  o[ob+2] = f2bf(v.z); o[ob+3] = f2bf(v.w);
}

// W[k][c][d] f32 -> bf16 in MFMA B-fragment order:
// frag f = ks*4+nt, lane = ((c>>3)&3)*16 + (d&15), elem e = c&7
__global__ void k_wfrag(const float* __restrict__ w, ushort_t* __restrict__ o, int total) {
  int i = blockIdx.x*blockDim.x + threadIdx.x;
  if (i >= total) return;
  int k = i >> 12, r = i & 4095, c = r >> 6, d = r & 63;
  int nt = d >> 4, lp = d & 15, ks = c >> 5, hi = (c >> 3) & 3, e = c & 7;
  int fi = ks*4 + nt, lane = hi*16 + lp;
  o[(size_t)(k*8 + fi)*512 + lane*8 + e] = f2bf(w[i]);
}

// up-projection: y[8p+c8] = relu(feats_sorted[p] @ W_up[c8] + b_up), stored bf16
__global__ __launch_bounds__(256) void k_up(const ushort_t* __restrict__ featb,
    const ushort_t* __restrict__ wupf, const float* __restrict__ bup,
    ushort_t* __restrict__ y)
{
  int wave = threadIdx.x >> 6, lane = threadIdx.x & 63;
  int n0 = blockIdx.x*64 + wave*16;
  if (n0 >= NPARENT) return;
  int lp = lane & 15, hi = lane >> 4;
  const ushort_t* ar = featb + (size_t)(n0+lp)*64 + hi*8;
  bf16x8 a0 = *(const bf16x8*)(ar);
  bf16x8 a1 = *(const bf16x8*)(ar + 32);
  float bv[4];
  #pragma unroll
  for (int nt=0; nt<4; ++nt) bv[nt] = bup[nt*16+lp];
  for (int c8=0; c8<8; ++c8) {
    const ushort_t* wb = wupf + (size_t)c8*4096 + lane*8;
    f32x4 acc[4];
    #pragma unroll
    for (int nt=0;nt<4;++nt) acc[nt] = (f32x4){0.f,0.f,0.f,0.f};
    #pragma unroll
    for (int nt=0;nt<4;++nt)
      acc[nt] = __builtin_amdgcn_mfma_f32_16x16x32_bf16(a0, *(const bf16x8*)(wb + nt*512), acc[nt], 0,0,0);
    #pragma unroll
    for (int nt=0;nt<4;++nt)
      acc[nt] = __builtin_amdgcn_mfma_f32_16x16x32_bf16(a1, *(const bf16x8*)(wb + (4+nt)*512), acc[nt], 0,0,0);
    #pragma unroll
    for (int nt=0;nt<4;++nt) {
      #pragma unroll
      for (int j=0;j<4;++j) {
        int par = n0 + hi*4 + j;
        float v = acc[nt][j] + bv[nt];
        v = fmaxf(v, 0.f);
        y[(size_t)(par*8 + c8)*64 + nt*16 + lp] = f2bf(v);
      }
    }
  }
}

// sparse stride-1 conv as gather-GEMM over sorted rows. Wave = 64 rows x 64 cols.
// Pipelined: aoff(k+1) computed during iter k; A(k) loads issue at the very top
// of iter k (addresses already in regs), so nbr-ds-read + B ds_reads + VALU run
// under the in-flight gathers. B double-buffered in LDS via global_load_lds.
template<int RELU, int SCATTER, typename OUT_T>
__global__ __launch_bounds__(256) void k_conv(const int4* __restrict__ cs,
    const int* __restrict__ tbl, const ushort_t* __restrict__ fin,
    const ushort_t* __restrict__ wf, const float* __restrict__ bias,
    OUT_T* __restrict__ out)
{
  __shared__ __align__(16) int nbrs[32*27];          // block parents x 27 neighbor ranks
  __shared__ __align__(16) ushort_t bbuf[2][4096];   // 8KB B double buffer

  // bijective XCD swizzle: nwg = 1875 = 8*234+3 (m204 variant)
  int bid = blockIdx.x;
  int xcd = bid & 7, jj = bid >> 3;
  int wg = (xcd < 3 ? xcd*235 : 705 + (xcd-3)*234) + jj;

  int tid = threadIdx.x;
  int wave = tid >> 6, lane = tid & 63;
  int m0 = wg*256 + wave*64;
  int lp = lane & 15, hi = lane >> 4;
  int pblk0 = wg*32;                                  // block's first sorted parent

  // ---- one-time: build neighbor-rank cache (864 entries) ----
  for (int i = tid; i < 32*27; i += 256) {
    int p = i / 27, j = i - p*27;
    int4 cc = cs[pblk0 + p];
    int dx = j/9 - 1, dy = (j/3)%3 - 1, dz = j%3 - 1;
    nbrs[i] = tbl[((cc.x+dx+1)*66 + (cc.y+dy+1))*66 + (cc.z+dz+1)];
  }

  // ---- stage B for k=0 into buf 0 (each wave stages 2 of 8 1KB chunks) ----
  {
    const char* wb = (const char*)wf;
    #pragma unroll
    for (int j=0;j<2;++j) {
      int chunk = wave*2 + j;
      gl2lds16(wb + (size_t)chunk*1024 + lane*16, &bbuf[0][chunk*512]);
    }
  }

  // per-lane constants: child bits (constant across subtiles), parent base
  int cx = (lp>>2)&1, cy = (lp>>1)&1, cz = lp&1, c = lp&7;
  int plbase = wave*8 + (lp>>3);                      // block-local parent, + s*2 per subtile

  f32x4 acc[4][4];
  #pragma unroll
  for (int s=0;s<4;++s)
    #pragma unroll
    for (int nt=0;nt<4;++nt) acc[s][nt] = (f32x4){0.f,0.f,0.f,0.f};

  const char* finl = (const char*)fin + hi*16;

  __syncthreads();   // nbrs + buf0 ready (barrier drains vmcnt)

  // aoff for k=0 (from LDS nbr cache)
  uint32_t aoffc[4];
  {
    int idx = ((cx-1)>>1)*9 + ((cy-1)>>1)*3 + ((cz-1)>>1) + 13;
    int cpx = c ^ 7;
    #pragma unroll
    for (int s=0;s<4;++s) {
      int rank = nbrs[(plbase + s*2)*27 + idx];
      uint32_t off = (uint32_t)(rank*8 + cpx) * 128u;
      aoffc[s] = (rank < 0) ? (uint32_t)ZIDX*128u : off;
    }
  }

  #pragma unroll 1
  for (int k=0;k<27;++k) {
    int cur = k & 1;
    // (1) A gathers for THIS k issue first — addresses were ready at entry
    bf16x8 a[4][2];
    #pragma unroll
    for (int s=0;s<4;++s) {
      a[s][0] = *(const bf16x8*)(finl + aoffc[s]);
      a[s][1] = *(const bf16x8*)(finl + aoffc[s] + 64);
    }
    // (2) stage next k's B chunks immediately (max time before barrier drain)
    if (k < 26) {
      const char* wb = (const char*)wf + (size_t)(k+1)*8192;
      #pragma unroll
      for (int j=0;j<2;++j) {
        int chunk = wave*2 + j;
        gl2lds16(wb + (size_t)chunk*1024 + lane*16, &bbuf[cur^1][chunk*512]);
      }
    }
    // (3) B fragments from LDS (stride-16B, conflict-free)
    bf16x8 bfr[8];
    #pragma unroll
    for (int f=0;f<8;++f) bfr[f] = *(const bf16x8*)&bbuf[cur][f*512 + lane*8];
    // (4) compute NEXT k's A offsets (ds_read latency hidden under gathers/MFMA)
    uint32_t aoffn[4];
    if (k < 26) {
      int k2 = k+1;
      int ox = k2/9 - 1, oy = (k2/3)%3 - 1, oz = k2%3 - 1;
      int xk = ((ox&1)<<2) | ((oy&1)<<1) | (oz&1);
      int cpx = c ^ xk;
      int idx = ((cx+ox)>>1)*9 + ((cy+oy)>>1)*3 + ((cz+oz)>>1) + 13;
      #pragma unroll
      for (int s=0;s<4;++s) {
        int rank = nbrs[(plbase + s*2)*27 + idx];
        uint32_t off = (uint32_t)(rank*8 + cpx) * 128u;
        aoffn[s] = (rank < 0) ? (uint32_t)ZIDX*128u : off;
      }
    }
    // (5) MFMAs (vmcnt wait here covers only the residual A latency)
    #pragma unroll
    for (int s=0;s<4;++s)
      #pragma unroll
      for (int nt=0;nt<4;++nt)
        acc[s][nt] = __builtin_amdgcn_mfma_f32_16x16x32_bf16(a[s][0], bfr[nt], acc[s][nt], 0,0,0);
    #pragma unroll
    for (int s=0;s<4;++s)
      #pragma unroll
      for (int nt=0;nt<4;++nt)
        acc[s][nt] = __builtin_amdgcn_mfma_f32_16x16x32_bf16(a[s][1], bfr[4+nt], acc[s][nt], 0,0,0);

    #pragma unroll
    for (int s=0;s<4;++s) aoffc[s] = aoffn[s];

    __syncthreads();   // drains stage loads; buf[cur^1] ready for next k
  }

  float bv[4];
  #pragma unroll
  for (int nt=0;nt<4;++nt) bv[nt] = bias[nt*16+lp];
  #pragma unroll
  for (int s=0;s<4;++s) {
    #pragma unroll
    for (int j=0;j<4;++j) {
      int row = m0 + s*16 + hi*4 + j;
      size_t rb;
      if constexpr (SCATTER) {
        int4 cc = cs[row >> 3];
        rb = ((size_t)cc.w*8 + (row & 7)) * 64;
      } else {
        rb = (size_t)row * 64;
      }
      #pragma unroll
      for (int nt=0;nt<4;++nt) {
        float v = acc[s][nt][j] + bv[nt];
        if (RELU) v = fmaxf(v, 0.f);
        size_t oi = rb + nt*16 + lp;
        if constexpr (sizeof(OUT_T)==2) ((ushort_t*)out)[oi] = f2bf(v);
        else                            out[oi] = v;
      }
    }
  }
}

extern "C" void kernel_launch(void* const* d_in, const int* in_sizes, int n_in,
                              void* d_out, int out_size, void* d_ws, size_t ws_size,
                              hipStream_t stream) {
  const int*   coords = (const int*)d_in[0];
  const float* feats  = (const float*)d_in[1];
  const float* Wup    = (const float*)d_in[2];
  const float* bup    = (const float*)d_in[3];
  const float* W1     = (const float*)d_in[4];
  const float* b1     = (const float*)d_in[5];
  const float* W2     = (const float*)d_in[6];
  const float* b2     = (const float*)d_in[7];
  char* ws = (char*)d_ws;
  if (ws_size < WS_NEED) return;   // fail visibly rather than corrupt

  int*      tbl  = (int*)(ws + OFF_TABLE);
  int4*     cs   = (int4*)(ws + OFF_CS);
  int*      hist = (int*)(ws + OFF_HIST);
  int*      cnt  = (int*)(ws + OFF_CNT);
  ushort_t* y    = (ushort_t*)(ws + OFF_Y);
  ushort_t* z    = (ushort_t*)(ws + OFF_Z);
  ushort_t* fb   = (ushort_t*)(ws + OFF_FEATB);
  ushort_t* wupf = (ushort_t*)(ws + OFF_WUPF);
  ushort_t* w1f  = (ushort_t*)(ws + OFF_W1F);
  ushort_t* w2f  = (ushort_t*)(ws + OFF_W2F);

  hipMemsetAsync(tbl, 0xFF, (size_t)TBL_N*4, stream);
  hipMemsetAsync(hist, 0, (size_t)NBIN*4, stream);
  k_zero<<<1,128,0,stream>>>(y, z);
  k_hist<<<(NPARENT+255)/256,256,0,stream>>>(coords, hist);
  k_scan<<<1,256,0,stream>>>(hist, cnt);
  k_rank<<<(NPARENT+255)/256,256,0,stream>>>(coords, cnt, cs, tbl);
  k_feats_bf16<<<(NPARENT*16+255)/256,256,0,stream>>>((const float4*)feats, cs, fb, NPARENT*16);
  k_wfrag<<<(8*4096+255)/256,256,0,stream>>>(Wup, wupf, 8*4096);
  k_wfrag<<<(27*4096+255)/256,256,0,stream>>>(W1, w1f, 27*4096);
  k_wfrag<<<(27*4096+255)/256,256,0,stream>>>(W2, w2f, 27*4096);
  k_up<<<(NPARENT+63)/64,256,0,stream>>>(fb, wupf, bup, y);
  k_conv<1,0,ushort_t><<<NOUT/256,256,0,stream>>>(cs, tbl, y,  w1f, b1, z);
  k_conv<0,1,float>   <<<NOUT/256,256,0,stream>>>(cs, tbl, z,  w2f, b2, (float*)d_out);
}

// Round 5
// 307.998 us; speedup vs baseline: 1.6883x; 1.2258x over previous
//
#include <hip/hip_runtime.h>
#include <stdint.h>

typedef __bf16 bf16x8 __attribute__((ext_vector_type(8)));
typedef float f32x4 __attribute__((ext_vector_type(4)));
typedef unsigned short ushort_t;

#define NPARENT 60000
#define NOUT (NPARENT*8)          // 480000 output rows
#define ZIDX NOUT                 // zero row index (missing neighbors)
#define ZOFF ((uint32_t)ZIDX*128u)
#define TBL_N (66*66*66)          // parent table, coords shifted +1
#define NBIN 4096                 // 16^3 Morton bins of 4^3 cells

static constexpr size_t OFF_TABLE = 0;                                      // 1,152,000 (padded)
static constexpr size_t OFF_CS    = 1152000;                                // int4 sorted coords, 960,000 B
static constexpr size_t OFF_Y     = OFF_CS + 960000;
// hist/cnt alias the head of Y: used only before k_up overwrites Y
static constexpr size_t OFF_HIST  = OFF_Y;
static constexpr size_t OFF_CNT   = OFF_Y + 16384;
static constexpr size_t OFF_Z     = OFF_Y + (size_t)(NOUT+1)*128;
static constexpr size_t OFF_FEATB = OFF_Z + (size_t)(NOUT+1)*128;
static constexpr size_t OFF_WUPF  = OFF_FEATB + (size_t)NPARENT*128;
static constexpr size_t OFF_W1F   = OFF_WUPF + (size_t)8*8192;
static constexpr size_t OFF_W2F   = OFF_W1F + (size_t)27*8192;
static constexpr size_t WS_NEED   = OFF_W2F + (size_t)27*8192;              // ~133.2 MB

__device__ __forceinline__ ushort_t f2bf(float x) {   // RNE float->bf16
  uint32_t u = __float_as_uint(x);
  u += 0x7fffu + ((u >> 16) & 1u);
  return (ushort_t)(u >> 16);
}

__device__ __forceinline__ int binof(int x, int y, int z) {  // 12-bit Morton of 4-cell bins
  int bx = x >> 2, by = y >> 2, bz = z >> 2, m = 0;
  #pragma unroll
  for (int b = 0; b < 4; ++b)
    m |= (((bx>>b)&1) << (3*b+2)) | (((by>>b)&1) << (3*b+1)) | (((bz>>b)&1) << (3*b));
  return m;
}

// async global->LDS, 16B per lane. dst is wave-uniform base (HW adds lane*16),
// src is this lane's global address.
__device__ __forceinline__ void gl2lds16(const void* g, void* l) {
  __builtin_amdgcn_global_load_lds(
      (const __attribute__((address_space(1))) uint32_t*)g,
      (__attribute__((address_space(3))) uint32_t*)l, 16, 0, 0);
}

__global__ void k_zero(ushort_t* y, ushort_t* z) {
  int t = threadIdx.x;
  if (t < 64) y[(size_t)ZIDX*64 + t] = 0;
  else        z[(size_t)ZIDX*64 + (t-64)] = 0;
}

__global__ void k_hist(const int* __restrict__ coords, int* __restrict__ hist) {
  int i = blockIdx.x*blockDim.x + threadIdx.x;
  if (i >= NPARENT) return;
  atomicAdd(&hist[binof(coords[3*i], coords[3*i+1], coords[3*i+2])], 1);
}

__global__ void k_scan(const int* __restrict__ hist, int* __restrict__ cnt) {
  __shared__ int s[256];
  int t = threadIdx.x;
  int loc[16], sum = 0;
  #pragma unroll
  for (int j=0;j<16;++j){ loc[j]=hist[t*16+j]; sum+=loc[j]; }
  s[t]=sum;
  __syncthreads();
  if (t==0){ int a=0; for (int i=0;i<256;++i){ int v=s[i]; s[i]=a; a+=v; } }
  __syncthreads();
  int a=s[t];
  #pragma unroll
  for (int j=0;j<16;++j){ cnt[t*16+j]=a; a+=loc[j]; }
}

// rank parents into Morton-bin order; emit packed sorted coords + orig idx, fill table with rank
__global__ void k_rank(const int* __restrict__ coords, int* __restrict__ cnt,
                       int4* __restrict__ cs, int* __restrict__ tbl) {
  int i = blockIdx.x*blockDim.x + threadIdx.x;
  if (i >= NPARENT) return;
  int x = coords[3*i], y = coords[3*i+1], z = coords[3*i+2];
  int r = atomicAdd(&cnt[binof(x,y,z)], 1);
  cs[r] = make_int4(x, y, z, i);
  tbl[((x+1)*66 + (y+1))*66 + (z+1)] = r;
}

// feats f32 -> bf16, gathered into sorted parent order
__global__ void k_feats_bf16(const float4* __restrict__ f, const int4* __restrict__ cs,
                             ushort_t* __restrict__ o, int total) {
  int t = blockIdx.x*blockDim.x + threadIdx.x;
  if (t >= total) return;
  int p = t >> 4, q = t & 15;
  int i = cs[p].w;
  float4 v = f[(size_t)i*16 + q];
  size_t ob = (size_t)p*64 + q*4;
  o[ob+0] = f2bf(v.x); o[ob+1] = f2bf(v.y);
  o[ob+2] = f2bf(v.z); o[ob+3] = f2bf(v.w);
}

// W[k][c][d] f32 -> bf16 in MFMA B-fragment order:
// frag f = ks*4+nt, lane = ((c>>3)&3)*16 + (d&15), elem e = c&7
__global__ void k_wfrag(const float* __restrict__ w, ushort_t* __restrict__ o, int total) {
  int i = blockIdx.x*blockDim.x + threadIdx.x;
  if (i >= total) return;
  int k = i >> 12, r = i & 4095, c = r >> 6, d = r & 63;
  int nt = d >> 4, lp = d & 15, ks = c >> 5, hi = (c >> 3) & 3, e = c & 7;
  int fi = ks*4 + nt, lane = hi*16 + lp;
  o[(size_t)(k*8 + fi)*512 + lane*8 + e] = f2bf(w[i]);
}

// up-projection: y[8p+c8] = relu(feats_sorted[p] @ W_up[c8] + b_up), stored bf16
__global__ __launch_bounds__(256) void k_up(const ushort_t* __restrict__ featb,
    const ushort_t* __restrict__ wupf, const float* __restrict__ bup,
    ushort_t* __restrict__ y)
{
  int wave = threadIdx.x >> 6, lane = threadIdx.x & 63;
  int n0 = blockIdx.x*64 + wave*16;
  if (n0 >= NPARENT) return;
  int lp = lane & 15, hi = lane >> 4;
  const ushort_t* ar = featb + (size_t)(n0+lp)*64 + hi*8;
  bf16x8 a0 = *(const bf16x8*)(ar);
  bf16x8 a1 = *(const bf16x8*)(ar + 32);
  float bv[4];
  #pragma unroll
  for (int nt=0; nt<4; ++nt) bv[nt] = bup[nt*16+lp];
  for (int c8=0; c8<8; ++c8) {
    const ushort_t* wb = wupf + (size_t)c8*4096 + lane*8;
    f32x4 acc[4];
    #pragma unroll
    for (int nt=0;nt<4;++nt) acc[nt] = (f32x4){0.f,0.f,0.f,0.f};
    #pragma unroll
    for (int nt=0;nt<4;++nt)
      acc[nt] = __builtin_amdgcn_mfma_f32_16x16x32_bf16(a0, *(const bf16x8*)(wb + nt*512), acc[nt], 0,0,0);
    #pragma unroll
    for (int nt=0;nt<4;++nt)
      acc[nt] = __builtin_amdgcn_mfma_f32_16x16x32_bf16(a1, *(const bf16x8*)(wb + (4+nt)*512), acc[nt], 0,0,0);
    #pragma unroll
    for (int nt=0;nt<4;++nt) {
      #pragma unroll
      for (int j=0;j<4;++j) {
        int par = n0 + hi*4 + j;
        float v = acc[nt][j] + bv[nt];
        v = fmaxf(v, 0.f);
        y[(size_t)(par*8 + c8)*64 + nt*16 + lp] = f2bf(v);
      }
    }
  }
}

// sparse stride-1 conv as gather-GEMM over sorted rows. Wave = 64 rows x 64 cols.
// TA-segment reduction: block's own 256 input rows staged in LDS (XOR-swizzled
// via pre-swizzled global source); in-block neighbor reads served from LDS,
// out-of-block reads by global gather (in-block lanes' global addr -> zero row,
// collapsing their segments). B double-buffered in LDS; nbr ranks in LDS.
template<int RELU, int SCATTER, typename OUT_T>
__global__ __launch_bounds__(256) void k_conv(const int4* __restrict__ cs,
    const int* __restrict__ tbl, const ushort_t* __restrict__ fin,
    const ushort_t* __restrict__ wf, const float* __restrict__ bias,
    OUT_T* __restrict__ out)
{
  __shared__ __align__(16) int nbrs[32*27];          // block parents x 27 neighbor ranks
  __shared__ __align__(16) ushort_t bbuf[2][4096];   // 8KB B double buffer
  __shared__ __align__(16) ushort_t abuf[256*64];    // 32KB own-rows cache (swizzled)

  // bijective XCD swizzle: nwg = 1875 = 8*234+3 (m204 variant)
  int bid = blockIdx.x;
  int xcd = bid & 7, jj = bid >> 3;
  int wg = (xcd < 3 ? xcd*235 : 705 + (xcd-3)*234) + jj;

  int tid = threadIdx.x;
  int wave = tid >> 6, lane = tid & 63;
  int m0 = wg*256 + wave*64;
  int lp = lane & 15, hi = lane >> 4;
  int pblk0 = wg*32;                                  // block's first sorted parent

  // ---- one-time: build neighbor-rank cache (864 entries) ----
  for (int i = tid; i < 32*27; i += 256) {
    int p = i / 27, j = i - p*27;
    int4 cc = cs[pblk0 + p];
    int dx = j/9 - 1, dy = (j/3)%3 - 1, dz = j%3 - 1;
    nbrs[i] = tbl[((cc.x+dx+1)*66 + (cc.y+dy+1))*66 + (cc.z+dz+1)];
  }

  // ---- one-time: stage own 256 input rows (32KB), source pre-XOR-swizzled ----
  // LDS linear dest; global src chunk = c ^ (rowloc&7) so stride-128B ds_reads
  // land on distinct bank quads.
  {
    const char* ybase = (const char*)fin + (size_t)pblk0*1024;
    #pragma unroll
    for (int j=0;j<8;++j) {
      int rowloc = wave*64 + j*8 + (lane>>3);
      int c = lane & 7;
      gl2lds16(ybase + rowloc*128 + ((c ^ (rowloc&7))<<4),
               (char*)abuf + wave*8192 + j*1024);
    }
  }

  // ---- stage B for k=0 into buf 0 (each wave stages 2 of 8 1KB chunks) ----
  {
    const char* wb = (const char*)wf;
    #pragma unroll
    for (int j=0;j<2;++j) {
      int chunk = wave*2 + j;
      gl2lds16(wb + (size_t)chunk*1024 + lane*16, &bbuf[0][chunk*512]);
    }
  }

  // per-lane constants: child bits (constant across subtiles), parent base
  int cx = (lp>>2)&1, cy = (lp>>1)&1, cz = lp&1, c = lp&7;
  int plbase = wave*8 + (lp>>3);                      // block-local parent, + s*2 per subtile

  f32x4 acc[4][4];
  #pragma unroll
  for (int s=0;s<4;++s)
    #pragma unroll
    for (int nt=0;nt<4;++nt) acc[s][nt] = (f32x4){0.f,0.f,0.f,0.f};

  const char* finl = (const char*)fin + hi*16;
  const char* abufc = (const char*)abuf;

  __syncthreads();   // nbrs + abuf + buf0 ready (barrier drains vmcnt)

  // pipelined per-k state: global byte offset, lds row base, in-block flag, chunk xors
  uint32_t agc[4]; uint32_t alc[4]; bool ibc[4];
  uint32_t x0c, x1c;
  {
    int xk = 7, cpx = c ^ xk;
    int idx = ((cx-1)>>1)*9 + ((cy-1)>>1)*3 + ((cz-1)>>1) + 13;
    x0c = (uint32_t)((hi ^ cpx) << 4);
    x1c = (uint32_t)(((hi+4) ^ cpx) << 4);
    #pragma unroll
    for (int s=0;s<4;++s) {
      int rank = nbrs[(plbase + s*2)*27 + idx];
      int rloc = rank - pblk0;
      bool ib = (unsigned)rloc < 32u;
      ibc[s] = ib;
      alc[s] = ib ? (uint32_t)((rloc*8 + cpx) << 7) : 0u;
      agc[s] = (ib || rank < 0) ? ZOFF : (uint32_t)(rank*8 + cpx) * 128u;
    }
  }

  #pragma unroll 1
  for (int k=0;k<27;++k) {
    int cur = k & 1;
    // (1) global A gathers for THIS k (in-block lanes point at zero row)
    bf16x8 g[4][2];
    #pragma unroll
    for (int s=0;s<4;++s) {
      g[s][0] = *(const bf16x8*)(finl + agc[s]);
      g[s][1] = *(const bf16x8*)(finl + agc[s] + 64);
    }
    // (2) stage next k's B chunks
    if (k < 26) {
      const char* wb = (const char*)wf + (size_t)(k+1)*8192;
      #pragma unroll
      for (int j=0;j<2;++j) {
        int chunk = wave*2 + j;
        gl2lds16(wb + (size_t)chunk*1024 + lane*16, &bbuf[cur^1][chunk*512]);
      }
    }
    // (3) B fragments from LDS
    bf16x8 bfr[8];
    #pragma unroll
    for (int f=0;f<8;++f) bfr[f] = *(const bf16x8*)&bbuf[cur][f*512 + lane*8];
    // (4) LDS A values for THIS k (swizzled chunks)
    bf16x8 l[4][2];
    #pragma unroll
    for (int s=0;s<4;++s) {
      l[s][0] = *(const bf16x8*)(abufc + alc[s] + x0c);
      l[s][1] = *(const bf16x8*)(abufc + alc[s] + x1c);
    }
    // (5) compute NEXT k's offsets
    uint32_t agn[4]; uint32_t aln[4]; bool ibn[4];
    uint32_t x0n = x0c, x1n = x1c;
    if (k < 26) {
      int k2 = k+1;
      int ox = k2/9 - 1, oy = (k2/3)%3 - 1, oz = k2%3 - 1;
      int xk = ((ox&1)<<2) | ((oy&1)<<1) | (oz&1);
      int cpx = c ^ xk;
      int idx = ((cx+ox)>>1)*9 + ((cy+oy)>>1)*3 + ((cz+oz)>>1) + 13;
      x0n = (uint32_t)((hi ^ cpx) << 4);
      x1n = (uint32_t)(((hi+4) ^ cpx) << 4);
      #pragma unroll
      for (int s=0;s<4;++s) {
        int rank = nbrs[(plbase + s*2)*27 + idx];
        int rloc = rank - pblk0;
        bool ib = (unsigned)rloc < 32u;
        ibn[s] = ib;
        aln[s] = ib ? (uint32_t)((rloc*8 + cpx) << 7) : 0u;
        agn[s] = (ib || rank < 0) ? ZOFF : (uint32_t)(rank*8 + cpx) * 128u;
      }
    } else {
      #pragma unroll
      for (int s=0;s<4;++s) { agn[s]=agc[s]; aln[s]=alc[s]; ibn[s]=ibc[s]; }
    }
    // (6) merge LDS/global per lane, (7) MFMA
    bf16x8 a[4][2];
    #pragma unroll
    for (int s=0;s<4;++s) {
      a[s][0] = ibc[s] ? l[s][0] : g[s][0];
      a[s][1] = ibc[s] ? l[s][1] : g[s][1];
    }
    #pragma unroll
    for (int s=0;s<4;++s)
      #pragma unroll
      for (int nt=0;nt<4;++nt)
        acc[s][nt] = __builtin_amdgcn_mfma_f32_16x16x32_bf16(a[s][0], bfr[nt], acc[s][nt], 0,0,0);
    #pragma unroll
    for (int s=0;s<4;++s)
      #pragma unroll
      for (int nt=0;nt<4;++nt)
        acc[s][nt] = __builtin_amdgcn_mfma_f32_16x16x32_bf16(a[s][1], bfr[4+nt], acc[s][nt], 0,0,0);

    #pragma unroll
    for (int s=0;s<4;++s) { agc[s]=agn[s]; alc[s]=aln[s]; ibc[s]=ibn[s]; }
    x0c = x0n; x1c = x1n;

    __syncthreads();   // drains stage loads; buf[cur^1] ready for next k
  }

  float bv[4];
  #pragma unroll
  for (int nt=0;nt<4;++nt) bv[nt] = bias[nt*16+lp];
  #pragma unroll
  for (int s=0;s<4;++s) {
    #pragma unroll
    for (int j=0;j<4;++j) {
      int row = m0 + s*16 + hi*4 + j;
      size_t rb;
      if constexpr (SCATTER) {
        int4 cc = cs[row >> 3];
        rb = ((size_t)cc.w*8 + (row & 7)) * 64;
      } else {
        rb = (size_t)row * 64;
      }
      #pragma unroll
      for (int nt=0;nt<4;++nt) {
        float v = acc[s][nt][j] + bv[nt];
        if (RELU) v = fmaxf(v, 0.f);
        size_t oi = rb + nt*16 + lp;
        if constexpr (sizeof(OUT_T)==2) ((ushort_t*)out)[oi] = f2bf(v);
        else                            out[oi] = v;
      }
    }
  }
}

extern "C" void kernel_launch(void* const* d_in, const int* in_sizes, int n_in,
                              void* d_out, int out_size, void* d_ws, size_t ws_size,
                              hipStream_t stream) {
  const int*   coords = (const int*)d_in[0];
  const float* feats  = (const float*)d_in[1];
  const float* Wup    = (const float*)d_in[2];
  const float* bup    = (const float*)d_in[3];
  const float* W1     = (const float*)d_in[4];
  const float* b1     = (const float*)d_in[5];
  const float* W2     = (const float*)d_in[6];
  const float* b2     = (const float*)d_in[7];
  char* ws = (char*)d_ws;
  if (ws_size < WS_NEED) return;   // fail visibly rather than corrupt

  int*      tbl  = (int*)(ws + OFF_TABLE);
  int4*     cs   = (int4*)(ws + OFF_CS);
  int*      hist = (int*)(ws + OFF_HIST);
  int*      cnt  = (int*)(ws + OFF_CNT);
  ushort_t* y    = (ushort_t*)(ws + OFF_Y);
  ushort_t* z    = (ushort_t*)(ws + OFF_Z);
  ushort_t* fb   = (ushort_t*)(ws + OFF_FEATB);
  ushort_t* wupf = (ushort_t*)(ws + OFF_WUPF);
  ushort_t* w1f  = (ushort_t*)(ws + OFF_W1F);
  ushort_t* w2f  = (ushort_t*)(ws + OFF_W2F);

  hipMemsetAsync(tbl, 0xFF, (size_t)TBL_N*4, stream);
  hipMemsetAsync(hist, 0, (size_t)NBIN*4, stream);
  k_zero<<<1,128,0,stream>>>(y, z);
  k_hist<<<(NPARENT+255)/256,256,0,stream>>>(coords, hist);
  k_scan<<<1,256,0,stream>>>(hist, cnt);
  k_rank<<<(NPARENT+255)/256,256,0,stream>>>(coords, cnt, cs, tbl);
  k_feats_bf16<<<(NPARENT*16+255)/256,256,0,stream>>>((const float4*)feats, cs, fb, NPARENT*16);
  k_wfrag<<<(8*4096+255)/256,256,0,stream>>>(Wup, wupf, 8*4096);
  k_wfrag<<<(27*4096+255)/256,256,0,stream>>>(W1, w1f, 27*4096);
  k_wfrag<<<(27*4096+255)/256,256,0,stream>>>(W2, w2f, 27*4096);
  k_up<<<(NPARENT+63)/64,256,0,stream>>>(fb, wupf, bup, y);
  k_conv<1,0,ushort_t><<<NOUT/256,256,0,stream>>>(cs, tbl, y,  w1f, b1, z);
  k_conv<0,1,float>   <<<NOUT/256,256,0,stream>>>(cs, tbl, z,  w2f, b2, (float*)d_out);
}